// Round 1
// baseline (169.167 us; speedup 1.0000x reference)
//
#include <hip/hip_runtime.h>

#define N_NODES 5000
#define N_EDGES 160000
#define HID 64
#define BATCH 512

// ---------------- graph prep ----------------

__global__ void count_kernel(const int* __restrict__ ei, int* __restrict__ deg) {
    int e = blockIdx.x * 256 + threadIdx.x;
    if (e < N_EDGES) atomicAdd(&deg[ei[N_EDGES + e]], 1);
}

__global__ void scan_kernel(const int* __restrict__ deg, int* __restrict__ row_start) {
    // single block, 1024 threads; exclusive scan of 5000 degrees
    __shared__ int sh[1024];
    __shared__ int s_carry;
    if (threadIdx.x == 0) s_carry = 0;
    __syncthreads();
    for (int base = 0; base < N_NODES; base += 1024) {
        int i = base + (int)threadIdx.x;
        int v = (i < N_NODES) ? deg[i] : 0;
        sh[threadIdx.x] = v;
        __syncthreads();
        for (int off = 1; off < 1024; off <<= 1) {
            int t = (threadIdx.x >= (unsigned)off) ? sh[threadIdx.x - off] : 0;
            __syncthreads();
            sh[threadIdx.x] += t;
            __syncthreads();
        }
        int incl = sh[threadIdx.x];
        int carry = s_carry;
        if (i < N_NODES) row_start[i] = carry + incl - v;
        __syncthreads();
        if (threadIdx.x == 1023) s_carry = carry + sh[1023];
        __syncthreads();
    }
}

__global__ void reorder_kernel(const int* __restrict__ ei, const int* __restrict__ row_start,
                               int* __restrict__ cursor, int* __restrict__ sorted_src) {
    int e = blockIdx.x * 256 + threadIdx.x;
    if (e < N_EDGES) {
        int dst = ei[N_EDGES + e];
        int pos = atomicAdd(&cursor[dst], 1);
        sorted_src[row_start[dst] + pos] = ei[e];
    }
}

// ---------------- weight transposes (coalesced GEMM loops need W[k][h]) -------------

__global__ void transpose_kernel(const float* __restrict__ Wl1, const float* __restrict__ Wr1,
                                 const float* __restrict__ Wt1, const float* __restrict__ Wl2,
                                 const float* __restrict__ Wr2, const float* __restrict__ Wt2,
                                 const float* __restrict__ Wc1,
                                 float* __restrict__ Wl1T, float* __restrict__ Wr1T,
                                 float* __restrict__ Wt1T, float* __restrict__ Wl2T,
                                 float* __restrict__ Wr2T, float* __restrict__ Wt2T,
                                 float* __restrict__ Wc1hT, float* __restrict__ Wc1tT) {
    int k = blockIdx.x;    // 0..63 (input index)
    int h = threadIdx.x;   // 0..63 (output index)
    Wl2T[k * 64 + h]  = Wl2[h * 64 + k];
    Wr2T[k * 64 + h]  = Wr2[h * 64 + k];
    Wt2T[k * 64 + h]  = Wt2[h * 64 + k];
    Wc1hT[k * 64 + h] = Wc1[h * 128 + k];
    Wc1tT[k * 64 + h] = Wc1[h * 128 + 64 + k];
    if (k < 4) {
        Wl1T[k * 64 + h] = Wl1[h * 4 + k];
        Wr1T[k * 64 + h] = Wr1[h * 4 + k];
        Wt1T[k * 64 + h] = Wt1[h * 4 + k];
    }
}

// ---------------- SAGE layer 1 (4 -> 64) ----------------

__global__ __launch_bounds__(64) void layer1_kernel(
        const float* __restrict__ x, const int* __restrict__ deg,
        const int* __restrict__ row_start, const int* __restrict__ sorted_src,
        const float* __restrict__ Wl1T, const float* __restrict__ bl1,
        const float* __restrict__ Wr1T, float* __restrict__ h1) {
    int n = blockIdx.x;
    int lane = threadIdx.x;
    int d = deg[n];
    int s0 = row_start[n];
    int f = lane & 3;       // feature
    int g = lane >> 2;      // neighbor slot (16-way)
    float acc = 0.f;
    for (int j = g; j < d; j += 16) {
        int s = sorted_src[s0 + j];
        acc += x[s * 4 + f];
    }
    acc += __shfl_down(acc, 32);
    acc += __shfl_down(acc, 16);
    acc += __shfl_down(acc, 8);
    acc += __shfl_down(acc, 4);
    __shared__ float mean[4], xn[4];
    if (lane < 4) {
        mean[lane] = acc / fmaxf((float)d, 1.f);
        xn[lane] = x[n * 4 + lane];
    }
    __syncthreads();
    float v = bl1[lane];
#pragma unroll
    for (int ff = 0; ff < 4; ff++)
        v += mean[ff] * Wl1T[ff * 64 + lane] + xn[ff] * Wr1T[ff * 64 + lane];
    h1[n * 64 + lane] = fmaxf(v, 0.f);
}

// ---------------- SAGE layer 2 (64 -> 64) fused with h_part = h2 @ Wc1[:, :64].T ----

__global__ __launch_bounds__(64) void layer2_kernel(
        const float* __restrict__ h1, const int* __restrict__ deg,
        const int* __restrict__ row_start, const int* __restrict__ sorted_src,
        const float* __restrict__ Wl2T, const float* __restrict__ bl2,
        const float* __restrict__ Wr2T, const float* __restrict__ Wc1hT,
        float* __restrict__ h_part) {
    int n = blockIdx.x;
    int h = threadIdx.x;
    int d = deg[n];
    int s0 = row_start[n];
    float a0 = 0.f, a1 = 0.f, a2 = 0.f, a3 = 0.f;
    int j = 0;
    for (; j + 4 <= d; j += 4) {
        int e0 = sorted_src[s0 + j];
        int e1 = sorted_src[s0 + j + 1];
        int e2 = sorted_src[s0 + j + 2];
        int e3 = sorted_src[s0 + j + 3];
        a0 += h1[e0 * 64 + h];
        a1 += h1[e1 * 64 + h];
        a2 += h1[e2 * 64 + h];
        a3 += h1[e3 * 64 + h];
    }
    for (; j < d; j++) a0 += h1[sorted_src[s0 + j] * 64 + h];
    float m = (a0 + a1 + a2 + a3) / fmaxf((float)d, 1.f);

    __shared__ float shm[64], shh[64], shh2[64];
    shm[h] = m;
    shh[h] = h1[n * 64 + h];
    __syncthreads();
    float v = bl2[h];
#pragma unroll
    for (int k = 0; k < 64; k++)
        v += shm[k] * Wl2T[k * 64 + h] + shh[k] * Wr2T[k * 64 + h];
    float h2v = fmaxf(v, 0.f);
    shh2[h] = h2v;
    __syncthreads();
    float p = 0.f;
#pragma unroll
    for (int k = 0; k < 64; k++) p += shh2[k] * Wc1hT[k * 64 + h];
    h_part[n * 64 + h] = p;
}

// ---------------- task MLP + t-half of classifier layer 1 ----------------

__global__ __launch_bounds__(64) void task_kernel(
        const float* __restrict__ task_feat,
        const float* __restrict__ Wt1T, const float* __restrict__ bt1,
        const float* __restrict__ Wt2T, const float* __restrict__ bt2,
        const float* __restrict__ Wc1tT, const float* __restrict__ bc1,
        float* __restrict__ t_part) {
    int b = blockIdx.x;
    int h = threadIdx.x;
    __shared__ float s1[64], s2[64];
    float t0 = task_feat[b * 4 + 0];
    float t1 = task_feat[b * 4 + 1];
    float t2 = task_feat[b * 4 + 2];
    float t3 = task_feat[b * 4 + 3];
    float v = bt1[h] + t0 * Wt1T[h] + t1 * Wt1T[64 + h] + t2 * Wt1T[128 + h] + t3 * Wt1T[192 + h];
    s1[h] = fmaxf(v, 0.f);
    __syncthreads();
    float v2 = bt2[h];
#pragma unroll
    for (int k = 0; k < 64; k++) v2 += s1[k] * Wt2T[k * 64 + h];
    s2[h] = v2;   // no relu on second task layer
    __syncthreads();
    float p = bc1[h];
#pragma unroll
    for (int k = 0; k < 64; k++) p += s2[k] * Wc1tT[k * 64 + h];
    t_part[b * 64 + h] = p;
}

// ---------------- final scores: out[b,n] = sum_h relu(hp[n,h]+tp[b,h])*w[h] + bc2 ----

__global__ __launch_bounds__(256) void scores_kernel(
        const float* __restrict__ h_part, const float* __restrict__ t_part,
        const float* __restrict__ Wc2, const float* __restrict__ bc2,
        float* __restrict__ out) {
    int tid = threadIdx.x;
    int n = blockIdx.x * 256 + tid;
    bool valid = n < N_NODES;
    int nn = valid ? n : (N_NODES - 1);
    float hr[64];
    const float4* hp = (const float4*)(h_part + nn * 64);
#pragma unroll
    for (int i = 0; i < 16; i++) {
        float4 v = hp[i];
        hr[4 * i + 0] = v.x; hr[4 * i + 1] = v.y;
        hr[4 * i + 2] = v.z; hr[4 * i + 3] = v.w;
    }
    float b2 = bc2[0];
    int b0 = blockIdx.y * 16;
    for (int bb = 0; bb < 16; bb++) {
        const float* tp = t_part + (b0 + bb) * 64;   // wave-uniform -> s_loads
        float acc = 0.f;
#pragma unroll
        for (int h = 0; h < 64; h++)
            acc = fmaf(fmaxf(hr[h] + tp[h], 0.f), Wc2[h], acc);
        if (valid) out[(b0 + bb) * N_NODES + n] = acc + b2;
    }
}

// ---------------- launch ----------------

extern "C" void kernel_launch(void* const* d_in, const int* in_sizes, int n_in,
                              void* d_out, int out_size, void* d_ws, size_t ws_size,
                              hipStream_t stream) {
    const float* x    = (const float*)d_in[0];
    const int*   ei   = (const int*)d_in[1];      // int32 (JAX x64 disabled)
    const float* task = (const float*)d_in[2];
    const float* Wl1  = (const float*)d_in[3];
    const float* bl1  = (const float*)d_in[4];
    const float* Wr1  = (const float*)d_in[5];
    const float* Wl2  = (const float*)d_in[6];
    const float* bl2  = (const float*)d_in[7];
    const float* Wr2  = (const float*)d_in[8];
    const float* Wt1  = (const float*)d_in[9];
    const float* bt1  = (const float*)d_in[10];
    const float* Wt2  = (const float*)d_in[11];
    const float* bt2  = (const float*)d_in[12];
    const float* Wc1  = (const float*)d_in[13];
    const float* bc1  = (const float*)d_in[14];
    const float* Wc2  = (const float*)d_in[15];
    const float* bc2  = (const float*)d_in[16];
    float* out = (float*)d_out;

    char* ws = (char*)d_ws;
    int*   deg        = (int*)(ws + 0);          // 5000 ints
    int*   cursor     = (int*)(ws + 20000);      // 5000 ints (contiguous with deg for 1 memset)
    int*   row_start  = (int*)(ws + 40064);      // 5000 ints
    int*   sorted_src = (int*)(ws + 60160);      // 160000 ints
    float* h1         = (float*)(ws + 700416);   // 5000*64
    float* h_part     = (float*)(ws + 1980672);  // 5000*64
    float* t_part     = (float*)(ws + 3260928);  // 512*64
    float* Wl1T  = (float*)(ws + 3392256);
    float* Wr1T  = (float*)(ws + 3393280);
    float* Wt1T  = (float*)(ws + 3394304);
    float* Wl2T  = (float*)(ws + 3395328);
    float* Wr2T  = (float*)(ws + 3411712);
    float* Wt2T  = (float*)(ws + 3428096);
    float* Wc1hT = (float*)(ws + 3444480);
    float* Wc1tT = (float*)(ws + 3460864);

    hipMemsetAsync(ws, 0, 40000, stream);  // deg + cursor

    transpose_kernel<<<64, 64, 0, stream>>>(Wl1, Wr1, Wt1, Wl2, Wr2, Wt2, Wc1,
                                            Wl1T, Wr1T, Wt1T, Wl2T, Wr2T, Wt2T,
                                            Wc1hT, Wc1tT);
    count_kernel<<<(N_EDGES + 255) / 256, 256, 0, stream>>>(ei, deg);
    scan_kernel<<<1, 1024, 0, stream>>>(deg, row_start);
    reorder_kernel<<<(N_EDGES + 255) / 256, 256, 0, stream>>>(ei, row_start, cursor, sorted_src);
    layer1_kernel<<<N_NODES, 64, 0, stream>>>(x, deg, row_start, sorted_src, Wl1T, bl1, Wr1T, h1);
    layer2_kernel<<<N_NODES, 64, 0, stream>>>(h1, deg, row_start, sorted_src, Wl2T, bl2, Wr2T,
                                              Wc1hT, h_part);
    task_kernel<<<BATCH, 64, 0, stream>>>(task, Wt1T, bt1, Wt2T, bt2, Wc1tT, bc1, t_part);
    scores_kernel<<<dim3(20, 32), 256, 0, stream>>>(h_part, t_part, Wc2, bc2, out);
}